// Round 13
// baseline (290.057 us; speedup 1.0000x reference)
//
#include <hip/hip_runtime.h>

#define NT 256

// ---------------- workspace layout (float offsets) ----------------
#define WS_SPWT    0        // [128][64]  sp_w transposed: spwT[c][h] = sp_w[h][c]
#define WS_SC1     8192     // [128] bn1 scale
#define WS_SH1     8320     // [128] bn1 shift (conv_b folded)
#define WS_SC2     8448     // [128] bn2 scale
#define WS_SH2     8576     // [128] bn2 shift
#define WS_LIWT    8704     // [128][64]  li_wT[j][o] = li_w[o][j]
#define WS_TW1T    16896    // [150][64]  tda_w1T[i][o]
#define WS_TW2T    26496    // [64][32]   tda_w2T[j][o2]
#define WS_CW1T    28544    // [672][128] cls_w1T[j][c]
#define WS_TOTAL   114560   // end of transposed tables
#define WS_WG      114560   // [10] Wg window constants
#define WS_WBASE   114688   // [B][10][128] window features (persistent)
#define WS_CURBASE (114688 + 2048*1280)   // cur region (reused per group)
#define CUR_STRIDE 20480    // 64*320 floats per b

// ---------------- prep: transposes + BN folds + Wg ----------------
__global__ void prep_kernel(
    const float* __restrict__ conv_b, const float* __restrict__ bn1_g,
    const float* __restrict__ bn1_b,  const float* __restrict__ bn1_m,
    const float* __restrict__ bn1_v,  const float* __restrict__ sp_w,
    const float* __restrict__ li_w,   const float* __restrict__ tda_w1,
    const float* __restrict__ tda_w2, const float* __restrict__ cls_w1,
    const float* __restrict__ bn2_g,  const float* __restrict__ bn2_b,
    const float* __restrict__ bn2_m,  const float* __restrict__ bn2_v,
    float* __restrict__ ws)
{
    int i = blockIdx.x * NT + threadIdx.x;
    if (i > WS_TOTAL) return;
    if (i == WS_TOTAL) {                    // Wg[10]: data-independent li-bias windows
        float g = 0.f, sE = 0.f, sL = 0.f; int w = 0;
        for (int t = 0; t < 320; ++t) {
            g = fmaf(0.9f, g, 1.f);
            int pos = t & 31;
            if (pos < 16) sE += g; else sL += g;
            if (pos == 31) { ws[WS_WG + w] = sL - sE; ++w; sE = 0.f; sL = 0.f; }
        }
        return;
    }
    if (i < WS_SC1) {                       // spwT
        int c = i >> 6, h = i & 63;
        ws[i] = sp_w[h*128 + c];
    } else if (i < WS_SH1) {                // bn1 scale
        int c = i - WS_SC1;
        float vv = bn1_v[c] + 1e-5f;
        ws[i] = (float)((double)bn1_g[c] / sqrt((double)vv));
    } else if (i < WS_SC2) {                // bn1 shift
        int c = i - WS_SH1;
        float vv = bn1_v[c] + 1e-5f;
        double s = (double)bn1_g[c] / sqrt((double)vv);
        ws[i] = (float)(((double)conv_b[c] - (double)bn1_m[c])*s + (double)bn1_b[c]);
    } else if (i < WS_SH2) {                // bn2 scale
        int c = i - WS_SC2;
        float vv = bn2_v[c] + 1e-5f;
        ws[i] = (float)((double)bn2_g[c] / sqrt((double)vv));
    } else if (i < WS_LIWT) {               // bn2 shift
        int c = i - WS_SH2;
        float vv = bn2_v[c] + 1e-5f;
        double s = (double)bn2_g[c] / sqrt((double)vv);
        ws[i] = (float)((double)bn2_b[c] - (double)bn2_m[c]*s);
    } else if (i < WS_TW1T) {               // li_wT
        int t = i - WS_LIWT; int j = t >> 6, o = t & 63;
        ws[i] = li_w[o*128 + j];
    } else if (i < WS_TW2T) {               // tda_w1T
        int t = i - WS_TW1T; int r = t >> 6, o = t & 63;
        ws[i] = tda_w1[o*150 + r];
    } else if (i < WS_CW1T) {               // tda_w2T
        int t = i - WS_TW2T; int j = t >> 5, o = t & 31;
        ws[i] = tda_w2[o*64 + j];
    } else {                                // cls_w1T
        int t = i - WS_CW1T; int j = t >> 7, c = t & 127;
        ws[i] = cls_w1[c*672 + j];
    }
}

// ---------------- kernel A: whole-b conv + BN + ReLU + f32 projection --------
// one block per b; 5 chunks of 64 t, x double-buffered in registers so chunk
// k+1's loads hide under chunk k's projection. Thread (ic, tg): conv
// out-channels {2ic, 2ic+1} for its 16 t. Projection: lane = t, wave = 16-h
// tile, uniform weights via scalar loads. sp_b folded into acc init.
// writes cur[bi][h][t] (group-local bi)
__launch_bounds__(NT, 4)
__global__ void convproj_kernel(
    const float* __restrict__ x, const float* __restrict__ conv_w,
    const float* __restrict__ sp_b, const float* __restrict__ ws,
    float* __restrict__ cur, int b0)
{
    __shared__ float y_lds[128*65];   // 33.3 KB -> 4 blocks/CU

    const int tid = threadIdx.x;
    const int bi  = blockIdx.x;
    const int ic  = tid & 63;
    const int tg  = tid >> 6;
    const int lane = tid & 63;
    const int h0 = __builtin_amdgcn_readfirstlane((tid >> 6) << 4);

    // ---- per-block constants (loaded once for all 5 chunks) ----
    float w0[15], w1[15];
    #pragma unroll
    for (int k = 0; k < 15; ++k) {
        w0[k] = conv_w[(2*ic)*15 + k];
        w1[k] = conv_w[(2*ic + 1)*15 + k];
    }
    const float sA = ws[WS_SC1 + 2*ic],     hA = ws[WS_SH1 + 2*ic];
    const float sB = ws[WS_SC1 + 2*ic + 1], hB = ws[WS_SH1 + 2*ic + 1];
    const float4* bp = reinterpret_cast<const float4*>(sp_b + h0);
    const float4 b0v = bp[0], b1v = bp[1], b2v = bp[2], b3v = bp[3];

    const float* __restrict__ spwT = ws;   // [128][64]
    const float* xb = x + (size_t)(b0 + bi) * 20480 + ic;
    float* curb = cur + (size_t)bi * CUR_STRIDE;

    // ---- prologue: chunk 0 x window (lower guard) ----
    float xr0[30], xr1[30];
    #pragma unroll
    for (int r = 0; r < 30; ++r) {
        int t = tg*16 - 7 + r;
        xr0[r] = (t >= 0) ? xb[(size_t)t * 64] : 0.f;
    }

    #pragma unroll
    for (int chk = 0; chk < 5; ++chk) {
        float* xc = (chk & 1) ? xr1 : xr0;   // static after full unroll
        float* xn = (chk & 1) ? xr0 : xr1;

        // ---- conv + BN + ReLU -> y_lds[c][tt] ----
        #pragma unroll
        for (int j = 0; j < 16; ++j) {
            float a0 = 0.f, a1 = 0.f;
            #pragma unroll
            for (int k = 0; k < 15; ++k) {
                a0 = fmaf(xc[j + k], w0[k], a0);
                a1 = fmaf(xc[j + k], w1[k], a1);
            }
            int tt = tg*16 + j;
            y_lds[(2*ic)*65 + tt]     = fmaxf(fmaf(a0, sA, hA), 0.f);
            y_lds[(2*ic + 1)*65 + tt] = fmaxf(fmaf(a1, sB, hB), 0.f);
        }
        __syncthreads();

        // ---- prefetch next chunk's x (flies under the projection) ----
        if (chk < 4) {
            const int tbase = (chk + 1)*64 + tg*16 - 7;   // >= 57, only upper guard
            if (tbase + 29 < 320) {
                #pragma unroll
                for (int r = 0; r < 30; ++r)
                    xn[r] = xb[(size_t)(tbase + r) * 64];
            } else {
                #pragma unroll
                for (int r = 0; r < 30; ++r) {
                    int t = tbase + r;
                    xn[r] = (t < 320) ? xb[(size_t)t * 64] : 0.f;
                }
            }
        }

        // ---- projection: cur[tt=lane][h0..h0+15] = spb + sum_c y[tt][c]*w[c][h] ----
        {
            float acc[16];
            acc[0]=b0v.x;  acc[1]=b0v.y;  acc[2]=b0v.z;  acc[3]=b0v.w;
            acc[4]=b1v.x;  acc[5]=b1v.y;  acc[6]=b1v.z;  acc[7]=b1v.w;
            acc[8]=b2v.x;  acc[9]=b2v.y;  acc[10]=b2v.z; acc[11]=b2v.w;
            acc[12]=b3v.x; acc[13]=b3v.y; acc[14]=b3v.z; acc[15]=b3v.w;

            #pragma unroll 4
            for (int c = 0; c < 128; ++c) {
                float yv = y_lds[c*65 + lane];
                const float4* wp = reinterpret_cast<const float4*>(spwT + c*64 + h0);
                float4 q0 = wp[0], q1 = wp[1], q2 = wp[2], q3 = wp[3];
                acc[0]  = fmaf(yv, q0.x, acc[0]);
                acc[1]  = fmaf(yv, q0.y, acc[1]);
                acc[2]  = fmaf(yv, q0.z, acc[2]);
                acc[3]  = fmaf(yv, q0.w, acc[3]);
                acc[4]  = fmaf(yv, q1.x, acc[4]);
                acc[5]  = fmaf(yv, q1.y, acc[5]);
                acc[6]  = fmaf(yv, q1.z, acc[6]);
                acc[7]  = fmaf(yv, q1.w, acc[7]);
                acc[8]  = fmaf(yv, q2.x, acc[8]);
                acc[9]  = fmaf(yv, q2.y, acc[9]);
                acc[10] = fmaf(yv, q2.z, acc[10]);
                acc[11] = fmaf(yv, q2.w, acc[11]);
                acc[12] = fmaf(yv, q3.x, acc[12]);
                acc[13] = fmaf(yv, q3.y, acc[13]);
                acc[14] = fmaf(yv, q3.z, acc[14]);
                acc[15] = fmaf(yv, q3.w, acc[15]);
            }
            // coalesced stores: cur[bi][h0+j][chk*64+lane]
            float* cb = curb + (size_t)h0 * 320 + chk*64 + lane;
            #pragma unroll
            for (int j = 0; j < 16; ++j)
                cb[(size_t)j*320] = acc[j];
        }
        __syncthreads();   // protect y_lds before next chunk's conv writes
    }
}

// ---------------- kernel B: LIF scan, one wave per batch element ----------------
// sp_b already folded into cur
__device__ __forceinline__ void lif16(float4 n0, float4 n1, float4 n2, float4 n3,
    float& mf, float& ms, float& rlo, float& rhi,
    float& slo, float& shi)
{
    float v[16] = {n0.x,n0.y,n0.z,n0.w, n1.x,n1.y,n1.z,n1.w,
                   n2.x,n2.y,n2.z,n2.w, n3.x,n3.y,n3.z,n3.w};
    slo = 0.f; shi = 0.f;
    #pragma unroll
    for (int q = 0; q < 16; ++q) {
        float c = v[q];
        mf = fmaf(0.5f, mf, c);
        bool sf = mf >= 0.5f;
        ms = fmaf(0.9f, ms, c);
        bool ss = ms >= 1.0f;
        mf = sf ? 0.f : mf;
        ms = ss ? 0.f : ms;
        rlo = fmaf(0.9f, rlo, sf ? 1.f : 0.f);
        rhi = fmaf(0.9f, rhi, ss ? 1.f : 0.f);
        slo += rlo; shi += rhi;
    }
}

__global__ void scan_kernel(const float* __restrict__ cur,
                            float* __restrict__ W, int b0, int nb)
{
    const int wv = (int)((blockIdx.x * (unsigned)blockDim.x + threadIdx.x) >> 6);
    if (wv >= nb) return;
    const int lane = threadIdx.x & 63;
    const float* cb = cur + (size_t)wv * CUR_STRIDE + (size_t)lane * 320;
    float* Wb = W + (size_t)(b0 + wv) * 1280;

    float mf = 0.f, ms = 0.f, rlo = 0.f, rhi = 0.f;

    // double-buffered prefetch, 2 tiles (128B/lane) in flight
    float4 A0 = *reinterpret_cast<const float4*>(cb);
    float4 A1 = *reinterpret_cast<const float4*>(cb + 4);
    float4 A2 = *reinterpret_cast<const float4*>(cb + 8);
    float4 A3 = *reinterpret_cast<const float4*>(cb + 12);
    float4 B0 = *reinterpret_cast<const float4*>(cb + 16);
    float4 B1 = *reinterpret_cast<const float4*>(cb + 20);
    float4 B2 = *reinterpret_cast<const float4*>(cb + 24);
    float4 B3 = *reinterpret_cast<const float4*>(cb + 28);

    #pragma unroll 1
    for (int tb = 0; tb < 20; tb += 2) {
        float sE_lo, sE_hi, slo, shi;
        lif16(A0, A1, A2, A3, mf, ms, rlo, rhi, sE_lo, sE_hi);
        if (tb + 2 < 20) {
            const float* p = cb + (tb + 2) * 16;
            A0 = *reinterpret_cast<const float4*>(p);
            A1 = *reinterpret_cast<const float4*>(p + 4);
            A2 = *reinterpret_cast<const float4*>(p + 8);
            A3 = *reinterpret_cast<const float4*>(p + 12);
        }
        lif16(B0, B1, B2, B3, mf, ms, rlo, rhi, slo, shi);
        if (tb + 3 < 20) {
            const float* p = cb + (tb + 3) * 16;
            B0 = *reinterpret_cast<const float4*>(p);
            B1 = *reinterpret_cast<const float4*>(p + 4);
            B2 = *reinterpret_cast<const float4*>(p + 8);
            B3 = *reinterpret_cast<const float4*>(p + 12);
        }
        int wdx = tb >> 1;
        Wb[wdx*128 + lane]      = slo - sE_lo;
        Wb[wdx*128 + 64 + lane] = shi - sE_hi;
    }
}

// ---------------- kernel C: classifier epilogue, one block per b ----------------
__global__ void epilogue_kernel(
    const float* __restrict__ tda,    const float* __restrict__ li_b,
    const float* __restrict__ tda_b1, const float* __restrict__ tda_b2,
    const float* __restrict__ cls_b1, const float* __restrict__ cls_w2,
    const float* __restrict__ cls_b2, const float* __restrict__ ws,
    const float* __restrict__ W,      float* __restrict__ out)
{
    __shared__ float Wl[1280];
    __shared__ float t1[64], tf[32], dp[640], h1[128];
    const int b = blockIdx.x, tid = threadIdx.x;

    for (int i = tid; i < 1280; i += NT)
        Wl[i] = W[(size_t)b*1280 + i];
    __syncthreads();

    const float* __restrict__ liwT = ws + WS_LIWT;
    const float* __restrict__ tw1T = ws + WS_TW1T;
    const float* __restrict__ tw2T = ws + WS_TW2T;
    const float* __restrict__ cw1T = ws + WS_CW1T;
    const float* tdab = tda + b*150;

    if (tid < 64) {                     // tda layer 1
        float acc = tda_b1[tid];
        for (int i2 = 0; i2 < 150; ++i2)
            acc = fmaf(tdab[i2], tw1T[i2*64 + tid], acc);
        t1[tid] = fmaxf(acc, 0.f);
    }
    __syncthreads();
    if (tid < 32) {                     // tda layer 2
        float acc = tda_b2[tid];
        #pragma unroll 8
        for (int j = 0; j < 64; ++j)
            acc = fmaf(t1[j], tw2T[j*32 + tid], acc);
        tf[tid] = fmaxf(acc, 0.f);
    }
    // dp_feat = (1/16) * (li_w @ W + li_b * Wg)
    {
        int o = tid & 63;
        for (int w = tid >> 6; w < 10; w += 4) {
            float acc = li_b[o] * ws[WS_WG + w];
            #pragma unroll 4
            for (int j = 0; j < 128; ++j)
                acc = fmaf(Wl[w*128 + j], liwT[j*64 + o], acc);
            dp[w*64 + o] = 0.0625f * acc;
        }
    }
    __syncthreads();
    if (tid < 128) {                    // classifier layer 1 + BN2 + ReLU
        float acc = cls_b1[tid];
        for (int j = 0; j < 640; ++j)
            acc = fmaf(dp[j], cw1T[j*128 + tid], acc);
        #pragma unroll 4
        for (int j = 0; j < 32; ++j)
            acc = fmaf(tf[j], cw1T[(640 + j)*128 + tid], acc);
        float s2 = ws[WS_SC2 + tid], sh2 = ws[WS_SH2 + tid];
        h1[tid] = fmaxf(fmaf(acc, s2, sh2), 0.f);
    }
    __syncthreads();
    if (tid < 4) {                      // classifier layer 2
        float acc = cls_b2[tid];
        for (int c = 0; c < 128; ++c)
            acc = fmaf(h1[c], cls_w2[tid*128 + c], acc);
        out[b*4 + tid] = acc;
    }
}

extern "C" void kernel_launch(void* const* d_in, const int* in_sizes, int n_in,
                              void* d_out, int out_size, void* d_ws, size_t ws_size,
                              hipStream_t stream) {
    const float* x      = (const float*)d_in[0];
    const float* tda    = (const float*)d_in[1];
    const float* conv_w = (const float*)d_in[2];
    const float* conv_b = (const float*)d_in[3];
    const float* bn1_g  = (const float*)d_in[4];
    const float* bn1_b  = (const float*)d_in[5];
    const float* bn1_m  = (const float*)d_in[6];
    const float* bn1_v  = (const float*)d_in[7];
    const float* sp_w   = (const float*)d_in[8];
    const float* sp_b   = (const float*)d_in[9];
    const float* li_w   = (const float*)d_in[10];
    const float* li_b   = (const float*)d_in[11];
    const float* tda_w1 = (const float*)d_in[12];
    const float* tda_b1 = (const float*)d_in[13];
    const float* tda_w2 = (const float*)d_in[14];
    const float* tda_b2 = (const float*)d_in[15];
    const float* cls_w1 = (const float*)d_in[16];
    const float* cls_b1 = (const float*)d_in[17];
    const float* bn2_g  = (const float*)d_in[18];
    const float* bn2_b  = (const float*)d_in[19];
    const float* bn2_m  = (const float*)d_in[20];
    const float* bn2_v  = (const float*)d_in[21];
    const float* cls_w2 = (const float*)d_in[22];
    const float* cls_b2 = (const float*)d_in[23];
    float* ws  = (float*)d_ws;
    float* out = (float*)d_out;

    const int B = in_sizes[0] / (320 * 64);   // 2048

    prep_kernel<<<(WS_TOTAL + 1 + NT - 1)/NT, NT, 0, stream>>>(
        conv_b, bn1_g, bn1_b, bn1_m, bn1_v, sp_w,
        li_w, tda_w1, tda_w2, cls_w1,
        bn2_g, bn2_b, bn2_m, bn2_v, ws);

    // batch grouping to fit cur region into ws
    long cap = (long)(ws_size / 4) - (long)WS_CURBASE;
    int nbg = (int)(cap / CUR_STRIDE);
    if (nbg < 1) nbg = 1;
    if (nbg > B) nbg = B;

    for (int g0 = 0; g0 < B; g0 += nbg) {
        int nb = (B - g0 < nbg) ? (B - g0) : nbg;
        convproj_kernel<<<nb, NT, 0, stream>>>(
            x, conv_w, sp_b, ws, ws + WS_CURBASE, g0);
        scan_kernel<<<(nb + 3)/4, NT, 0, stream>>>(
            ws + WS_CURBASE, ws + WS_WBASE, g0, nb);
    }

    epilogue_kernel<<<B, NT, 0, stream>>>(
        tda, li_b, tda_b1, tda_b2, cls_b1, cls_w2, cls_b2,
        ws, ws + WS_WBASE, out);
}

// Round 14
// 289.698 us; speedup vs baseline: 1.0012x; 1.0012x over previous
//
#include <hip/hip_runtime.h>

#define NT 256

// ---------------- workspace layout (float offsets) ----------------
#define WS_SPWT    0        // [128][64]  sp_w transposed: spwT[c][h] = sp_w[h][c]
#define WS_SC1     8192     // [128] bn1 scale
#define WS_SH1     8320     // [128] bn1 shift (conv_b folded)
#define WS_SC2     8448     // [128] bn2 scale
#define WS_SH2     8576     // [128] bn2 shift
#define WS_LIWT    8704     // [128][64]  li_wT[j][o] = li_w[o][j]
#define WS_TW1T    16896    // [150][64]  tda_w1T[i][o]
#define WS_TW2T    26496    // [64][32]   tda_w2T[j][o2]
#define WS_CW1T    28544    // [672][128] cls_w1T[j][c]
#define WS_TOTAL   114560   // end of transposed tables
#define WS_WG      114560   // [10] Wg window constants
#define WS_WBASE   114688   // [B][10][128] window features (persistent)
#define WS_CURBASE (114688 + 2048*1280)   // cur region (reused per group)
#define CUR_STRIDE 20480    // 64*320 floats per b

// ---------------- prep: transposes + BN folds + Wg ----------------
__global__ void prep_kernel(
    const float* __restrict__ conv_b, const float* __restrict__ bn1_g,
    const float* __restrict__ bn1_b,  const float* __restrict__ bn1_m,
    const float* __restrict__ bn1_v,  const float* __restrict__ sp_w,
    const float* __restrict__ li_w,   const float* __restrict__ tda_w1,
    const float* __restrict__ tda_w2, const float* __restrict__ cls_w1,
    const float* __restrict__ bn2_g,  const float* __restrict__ bn2_b,
    const float* __restrict__ bn2_m,  const float* __restrict__ bn2_v,
    float* __restrict__ ws)
{
    int i = blockIdx.x * NT + threadIdx.x;
    if (i > WS_TOTAL) return;
    if (i == WS_TOTAL) {                    // Wg[10]: data-independent li-bias windows
        float g = 0.f, sE = 0.f, sL = 0.f; int w = 0;
        for (int t = 0; t < 320; ++t) {
            g = fmaf(0.9f, g, 1.f);
            int pos = t & 31;
            if (pos < 16) sE += g; else sL += g;
            if (pos == 31) { ws[WS_WG + w] = sL - sE; ++w; sE = 0.f; sL = 0.f; }
        }
        return;
    }
    if (i < WS_SC1) {                       // spwT
        int c = i >> 6, h = i & 63;
        ws[i] = sp_w[h*128 + c];
    } else if (i < WS_SH1) {                // bn1 scale
        int c = i - WS_SC1;
        float vv = bn1_v[c] + 1e-5f;
        ws[i] = (float)((double)bn1_g[c] / sqrt((double)vv));
    } else if (i < WS_SC2) {                // bn1 shift
        int c = i - WS_SH1;
        float vv = bn1_v[c] + 1e-5f;
        double s = (double)bn1_g[c] / sqrt((double)vv);
        ws[i] = (float)(((double)conv_b[c] - (double)bn1_m[c])*s + (double)bn1_b[c]);
    } else if (i < WS_SH2) {                // bn2 scale
        int c = i - WS_SC2;
        float vv = bn2_v[c] + 1e-5f;
        ws[i] = (float)((double)bn2_g[c] / sqrt((double)vv));
    } else if (i < WS_LIWT) {               // bn2 shift
        int c = i - WS_SH2;
        float vv = bn2_v[c] + 1e-5f;
        double s = (double)bn2_g[c] / sqrt((double)vv);
        ws[i] = (float)((double)bn2_b[c] - (double)bn2_m[c]*s);
    } else if (i < WS_TW1T) {               // li_wT
        int t = i - WS_LIWT; int j = t >> 6, o = t & 63;
        ws[i] = li_w[o*128 + j];
    } else if (i < WS_TW2T) {               // tda_w1T
        int t = i - WS_TW1T; int r = t >> 6, o = t & 63;
        ws[i] = tda_w1[o*150 + r];
    } else if (i < WS_CW1T) {               // tda_w2T
        int t = i - WS_TW2T; int j = t >> 5, o = t & 31;
        ws[i] = tda_w2[o*64 + j];
    } else {                                // cls_w1T
        int t = i - WS_CW1T; int j = t >> 7, c = t & 127;
        ws[i] = cls_w1[c*672 + j];
    }
}

// ---------------- kernel A: whole-b conv + BN + ReLU + f32 projection --------
// one block per b; 5 chunks of 64 t, x double-buffered in registers so chunk
// k+1's loads hide under chunk k's projection. Thread (ic, tg): conv
// out-channels {2ic, 2ic+1} for its 16 t. Projection: lane = t, wave = 16-h
// tile, uniform weights via scalar loads. sp_b folded into acc init.
// writes cur[bi][h][t] (group-local bi)
__launch_bounds__(NT, 4)
__global__ void convproj_kernel(
    const float* __restrict__ x, const float* __restrict__ conv_w,
    const float* __restrict__ sp_b, const float* __restrict__ ws,
    float* __restrict__ cur, int b0)
{
    __shared__ float y_lds[128*65];   // 33.3 KB -> 4 blocks/CU

    const int tid = threadIdx.x;
    const int bi  = blockIdx.x;
    const int ic  = tid & 63;
    const int tg  = tid >> 6;
    const int lane = tid & 63;
    const int h0 = __builtin_amdgcn_readfirstlane((tid >> 6) << 4);

    // ---- per-block constants (loaded once for all 5 chunks) ----
    float w0[15], w1[15];
    #pragma unroll
    for (int k = 0; k < 15; ++k) {
        w0[k] = conv_w[(2*ic)*15 + k];
        w1[k] = conv_w[(2*ic + 1)*15 + k];
    }
    const float sA = ws[WS_SC1 + 2*ic],     hA = ws[WS_SH1 + 2*ic];
    const float sB = ws[WS_SC1 + 2*ic + 1], hB = ws[WS_SH1 + 2*ic + 1];
    const float4* bp = reinterpret_cast<const float4*>(sp_b + h0);
    const float4 b0v = bp[0], b1v = bp[1], b2v = bp[2], b3v = bp[3];

    const float* __restrict__ spwT = ws;   // [128][64]
    const float* xb = x + (size_t)(b0 + bi) * 20480 + ic;
    float* curb = cur + (size_t)bi * CUR_STRIDE;

    // ---- prologue: chunk 0 x window (lower guard) ----
    float xr0[30], xr1[30];
    #pragma unroll
    for (int r = 0; r < 30; ++r) {
        int t = tg*16 - 7 + r;
        xr0[r] = (t >= 0) ? xb[(size_t)t * 64] : 0.f;
    }

    #pragma unroll
    for (int chk = 0; chk < 5; ++chk) {
        float* xc = (chk & 1) ? xr1 : xr0;   // static after full unroll
        float* xn = (chk & 1) ? xr0 : xr1;

        // ---- conv + BN + ReLU -> y_lds[c][tt] ----
        #pragma unroll
        for (int j = 0; j < 16; ++j) {
            float a0 = 0.f, a1 = 0.f;
            #pragma unroll
            for (int k = 0; k < 15; ++k) {
                a0 = fmaf(xc[j + k], w0[k], a0);
                a1 = fmaf(xc[j + k], w1[k], a1);
            }
            int tt = tg*16 + j;
            y_lds[(2*ic)*65 + tt]     = fmaxf(fmaf(a0, sA, hA), 0.f);
            y_lds[(2*ic + 1)*65 + tt] = fmaxf(fmaf(a1, sB, hB), 0.f);
        }
        __syncthreads();

        // ---- prefetch next chunk's x (flies under the projection) ----
        if (chk < 4) {
            const int tbase = (chk + 1)*64 + tg*16 - 7;   // >= 57, only upper guard
            if (tbase + 29 < 320) {
                #pragma unroll
                for (int r = 0; r < 30; ++r)
                    xn[r] = xb[(size_t)(tbase + r) * 64];
            } else {
                #pragma unroll
                for (int r = 0; r < 30; ++r) {
                    int t = tbase + r;
                    xn[r] = (t < 320) ? xb[(size_t)t * 64] : 0.f;
                }
            }
        }

        // ---- projection: cur[tt=lane][h0..h0+15] = spb + sum_c y[tt][c]*w[c][h] ----
        {
            float acc[16];
            acc[0]=b0v.x;  acc[1]=b0v.y;  acc[2]=b0v.z;  acc[3]=b0v.w;
            acc[4]=b1v.x;  acc[5]=b1v.y;  acc[6]=b1v.z;  acc[7]=b1v.w;
            acc[8]=b2v.x;  acc[9]=b2v.y;  acc[10]=b2v.z; acc[11]=b2v.w;
            acc[12]=b3v.x; acc[13]=b3v.y; acc[14]=b3v.z; acc[15]=b3v.w;

            #pragma unroll 4
            for (int c = 0; c < 128; ++c) {
                float yv = y_lds[c*65 + lane];
                const float4* wp = reinterpret_cast<const float4*>(spwT + c*64 + h0);
                float4 q0 = wp[0], q1 = wp[1], q2 = wp[2], q3 = wp[3];
                acc[0]  = fmaf(yv, q0.x, acc[0]);
                acc[1]  = fmaf(yv, q0.y, acc[1]);
                acc[2]  = fmaf(yv, q0.z, acc[2]);
                acc[3]  = fmaf(yv, q0.w, acc[3]);
                acc[4]  = fmaf(yv, q1.x, acc[4]);
                acc[5]  = fmaf(yv, q1.y, acc[5]);
                acc[6]  = fmaf(yv, q1.z, acc[6]);
                acc[7]  = fmaf(yv, q1.w, acc[7]);
                acc[8]  = fmaf(yv, q2.x, acc[8]);
                acc[9]  = fmaf(yv, q2.y, acc[9]);
                acc[10] = fmaf(yv, q2.z, acc[10]);
                acc[11] = fmaf(yv, q2.w, acc[11]);
                acc[12] = fmaf(yv, q3.x, acc[12]);
                acc[13] = fmaf(yv, q3.y, acc[13]);
                acc[14] = fmaf(yv, q3.z, acc[14]);
                acc[15] = fmaf(yv, q3.w, acc[15]);
            }
            // coalesced stores: cur[bi][h0+j][chk*64+lane]
            float* cb = curb + (size_t)h0 * 320 + chk*64 + lane;
            #pragma unroll
            for (int j = 0; j < 16; ++j)
                cb[(size_t)j*320] = acc[j];
        }
        __syncthreads();   // protect y_lds before next chunk's conv writes
    }
}

// ---------------- kernel B: LIF scan, one wave per batch element ----------------
// sp_b already folded into cur
__device__ __forceinline__ void lif16(float4 n0, float4 n1, float4 n2, float4 n3,
    float& mf, float& ms, float& rlo, float& rhi,
    float& slo, float& shi)
{
    float v[16] = {n0.x,n0.y,n0.z,n0.w, n1.x,n1.y,n1.z,n1.w,
                   n2.x,n2.y,n2.z,n2.w, n3.x,n3.y,n3.z,n3.w};
    slo = 0.f; shi = 0.f;
    #pragma unroll
    for (int q = 0; q < 16; ++q) {
        float c = v[q];
        mf = fmaf(0.5f, mf, c);
        bool sf = mf >= 0.5f;
        ms = fmaf(0.9f, ms, c);
        bool ss = ms >= 1.0f;
        mf = sf ? 0.f : mf;
        ms = ss ? 0.f : ms;
        rlo = fmaf(0.9f, rlo, sf ? 1.f : 0.f);
        rhi = fmaf(0.9f, rhi, ss ? 1.f : 0.f);
        slo += rlo; shi += rhi;
    }
}

__global__ void scan_kernel(const float* __restrict__ cur,
                            float* __restrict__ W, int b0, int nb)
{
    const int wv = (int)((blockIdx.x * (unsigned)blockDim.x + threadIdx.x) >> 6);
    if (wv >= nb) return;
    const int lane = threadIdx.x & 63;
    const float* cb = cur + (size_t)wv * CUR_STRIDE + (size_t)lane * 320;
    float* Wb = W + (size_t)(b0 + wv) * 1280;

    float mf = 0.f, ms = 0.f, rlo = 0.f, rhi = 0.f;

    // double-buffered prefetch, 2 tiles (128B/lane) in flight
    float4 A0 = *reinterpret_cast<const float4*>(cb);
    float4 A1 = *reinterpret_cast<const float4*>(cb + 4);
    float4 A2 = *reinterpret_cast<const float4*>(cb + 8);
    float4 A3 = *reinterpret_cast<const float4*>(cb + 12);
    float4 B0 = *reinterpret_cast<const float4*>(cb + 16);
    float4 B1 = *reinterpret_cast<const float4*>(cb + 20);
    float4 B2 = *reinterpret_cast<const float4*>(cb + 24);
    float4 B3 = *reinterpret_cast<const float4*>(cb + 28);

    #pragma unroll 1
    for (int tb = 0; tb < 20; tb += 2) {
        float sE_lo, sE_hi, slo, shi;
        lif16(A0, A1, A2, A3, mf, ms, rlo, rhi, sE_lo, sE_hi);
        if (tb + 2 < 20) {
            const float* p = cb + (tb + 2) * 16;
            A0 = *reinterpret_cast<const float4*>(p);
            A1 = *reinterpret_cast<const float4*>(p + 4);
            A2 = *reinterpret_cast<const float4*>(p + 8);
            A3 = *reinterpret_cast<const float4*>(p + 12);
        }
        lif16(B0, B1, B2, B3, mf, ms, rlo, rhi, slo, shi);
        if (tb + 3 < 20) {
            const float* p = cb + (tb + 3) * 16;
            B0 = *reinterpret_cast<const float4*>(p);
            B1 = *reinterpret_cast<const float4*>(p + 4);
            B2 = *reinterpret_cast<const float4*>(p + 8);
            B3 = *reinterpret_cast<const float4*>(p + 12);
        }
        int wdx = tb >> 1;
        Wb[wdx*128 + lane]      = slo - sE_lo;
        Wb[wdx*128 + 64 + lane] = shi - sE_hi;
    }
}

// ---------------- kernel C: classifier epilogue, one block per b ----------------
__global__ void epilogue_kernel(
    const float* __restrict__ tda,    const float* __restrict__ li_b,
    const float* __restrict__ tda_b1, const float* __restrict__ tda_b2,
    const float* __restrict__ cls_b1, const float* __restrict__ cls_w2,
    const float* __restrict__ cls_b2, const float* __restrict__ ws,
    const float* __restrict__ W,      float* __restrict__ out)
{
    __shared__ float Wl[1280];
    __shared__ float t1[64], tf[32], dp[640], h1[128];
    const int b = blockIdx.x, tid = threadIdx.x;

    for (int i = tid; i < 1280; i += NT)
        Wl[i] = W[(size_t)b*1280 + i];
    __syncthreads();

    const float* __restrict__ liwT = ws + WS_LIWT;
    const float* __restrict__ tw1T = ws + WS_TW1T;
    const float* __restrict__ tw2T = ws + WS_TW2T;
    const float* __restrict__ cw1T = ws + WS_CW1T;
    const float* tdab = tda + b*150;

    if (tid < 64) {                     // tda layer 1
        float acc = tda_b1[tid];
        for (int i2 = 0; i2 < 150; ++i2)
            acc = fmaf(tdab[i2], tw1T[i2*64 + tid], acc);
        t1[tid] = fmaxf(acc, 0.f);
    }
    __syncthreads();
    if (tid < 32) {                     // tda layer 2
        float acc = tda_b2[tid];
        #pragma unroll 8
        for (int j = 0; j < 64; ++j)
            acc = fmaf(t1[j], tw2T[j*32 + tid], acc);
        tf[tid] = fmaxf(acc, 0.f);
    }
    // dp_feat = (1/16) * (li_w @ W + li_b * Wg)
    {
        int o = tid & 63;
        for (int w = tid >> 6; w < 10; w += 4) {
            float acc = li_b[o] * ws[WS_WG + w];
            #pragma unroll 4
            for (int j = 0; j < 128; ++j)
                acc = fmaf(Wl[w*128 + j], liwT[j*64 + o], acc);
            dp[w*64 + o] = 0.0625f * acc;
        }
    }
    __syncthreads();
    if (tid < 128) {                    // classifier layer 1 + BN2 + ReLU
        float acc = cls_b1[tid];
        for (int j = 0; j < 640; ++j)
            acc = fmaf(dp[j], cw1T[j*128 + tid], acc);
        #pragma unroll 4
        for (int j = 0; j < 32; ++j)
            acc = fmaf(tf[j], cw1T[(640 + j)*128 + tid], acc);
        float s2 = ws[WS_SC2 + tid], sh2 = ws[WS_SH2 + tid];
        h1[tid] = fmaxf(fmaf(acc, s2, sh2), 0.f);
    }
    __syncthreads();
    if (tid < 4) {                      // classifier layer 2
        float acc = cls_b2[tid];
        for (int c = 0; c < 128; ++c)
            acc = fmaf(h1[c], cls_w2[tid*128 + c], acc);
        out[b*4 + tid] = acc;
    }
}

extern "C" void kernel_launch(void* const* d_in, const int* in_sizes, int n_in,
                              void* d_out, int out_size, void* d_ws, size_t ws_size,
                              hipStream_t stream) {
    const float* x      = (const float*)d_in[0];
    const float* tda    = (const float*)d_in[1];
    const float* conv_w = (const float*)d_in[2];
    const float* conv_b = (const float*)d_in[3];
    const float* bn1_g  = (const float*)d_in[4];
    const float* bn1_b  = (const float*)d_in[5];
    const float* bn1_m  = (const float*)d_in[6];
    const float* bn1_v  = (const float*)d_in[7];
    const float* sp_w   = (const float*)d_in[8];
    const float* sp_b   = (const float*)d_in[9];
    const float* li_w   = (const float*)d_in[10];
    const float* li_b   = (const float*)d_in[11];
    const float* tda_w1 = (const float*)d_in[12];
    const float* tda_b1 = (const float*)d_in[13];
    const float* tda_w2 = (const float*)d_in[14];
    const float* tda_b2 = (const float*)d_in[15];
    const float* cls_w1 = (const float*)d_in[16];
    const float* cls_b1 = (const float*)d_in[17];
    const float* bn2_g  = (const float*)d_in[18];
    const float* bn2_b  = (const float*)d_in[19];
    const float* bn2_m  = (const float*)d_in[20];
    const float* bn2_v  = (const float*)d_in[21];
    const float* cls_w2 = (const float*)d_in[22];
    const float* cls_b2 = (const float*)d_in[23];
    float* ws  = (float*)d_ws;
    float* out = (float*)d_out;

    const int B = in_sizes[0] / (320 * 64);   // 2048

    prep_kernel<<<(WS_TOTAL + 1 + NT - 1)/NT, NT, 0, stream>>>(
        conv_b, bn1_g, bn1_b, bn1_m, bn1_v, sp_w,
        li_w, tda_w1, tda_w2, cls_w1,
        bn2_g, bn2_b, bn2_m, bn2_v, ws);

    // batch grouping to fit cur region into ws
    long cap = (long)(ws_size / 4) - (long)WS_CURBASE;
    int nbg = (int)(cap / CUR_STRIDE);
    if (nbg < 1) nbg = 1;
    if (nbg > B) nbg = B;

    for (int g0 = 0; g0 < B; g0 += nbg) {
        int nb = (B - g0 < nbg) ? (B - g0) : nbg;
        convproj_kernel<<<nb, NT, 0, stream>>>(
            x, conv_w, sp_b, ws, ws + WS_CURBASE, g0);
        scan_kernel<<<(nb + 3)/4, NT, 0, stream>>>(
            ws + WS_CURBASE, ws + WS_WBASE, g0, nb);
    }

    epilogue_kernel<<<B, NT, 0, stream>>>(
        tda, li_b, tda_b1, tda_b2, cls_b1, cls_w2, cls_b2,
        ws, ws + WS_WBASE, out);
}

// Round 15
// 249.731 us; speedup vs baseline: 1.1615x; 1.1600x over previous
//
#include <hip/hip_runtime.h>

#define NT 256

// ---------------- workspace layout (float offsets) ----------------
#define WS_SPWT    0        // [128][64]  sp_w transposed: spwT[c][h] = sp_w[h][c]
#define WS_SC1     8192     // [128] bn1 scale
#define WS_SH1     8320     // [128] bn1 shift (conv_b folded)
#define WS_SC2     8448     // [128] bn2 scale
#define WS_SH2     8576     // [128] bn2 shift
#define WS_LIWT    8704     // [128][64]  li_wT[j][o] = li_w[o][j]
#define WS_TW1T    16896    // [150][64]  tda_w1T[i][o]
#define WS_TW2T    26496    // [64][32]   tda_w2T[j][o2]
#define WS_CW1T    28544    // [672][128] cls_w1T[j][c]
#define WS_TOTAL   114560   // end of transposed tables
#define WS_WG      114560   // [10] Wg window constants
#define WS_WBASE   114688   // [B][10][128] window features

// ---------------- prep: transposes + BN folds + Wg ----------------
__global__ void prep_kernel(
    const float* __restrict__ conv_b, const float* __restrict__ bn1_g,
    const float* __restrict__ bn1_b,  const float* __restrict__ bn1_m,
    const float* __restrict__ bn1_v,  const float* __restrict__ sp_w,
    const float* __restrict__ li_w,   const float* __restrict__ tda_w1,
    const float* __restrict__ tda_w2, const float* __restrict__ cls_w1,
    const float* __restrict__ bn2_g,  const float* __restrict__ bn2_b,
    const float* __restrict__ bn2_m,  const float* __restrict__ bn2_v,
    float* __restrict__ ws)
{
    int i = blockIdx.x * NT + threadIdx.x;
    if (i > WS_TOTAL) return;
    if (i == WS_TOTAL) {                    // Wg[10]: data-independent li-bias windows
        float g = 0.f, sE = 0.f, sL = 0.f; int w = 0;
        for (int t = 0; t < 320; ++t) {
            g = fmaf(0.9f, g, 1.f);
            int pos = t & 31;
            if (pos < 16) sE += g; else sL += g;
            if (pos == 31) { ws[WS_WG + w] = sL - sE; ++w; sE = 0.f; sL = 0.f; }
        }
        return;
    }
    if (i < WS_SC1) {                       // spwT
        int c = i >> 6, h = i & 63;
        ws[i] = sp_w[h*128 + c];
    } else if (i < WS_SH1) {                // bn1 scale
        int c = i - WS_SC1;
        float vv = bn1_v[c] + 1e-5f;
        ws[i] = (float)((double)bn1_g[c] / sqrt((double)vv));
    } else if (i < WS_SC2) {                // bn1 shift
        int c = i - WS_SH1;
        float vv = bn1_v[c] + 1e-5f;
        double s = (double)bn1_g[c] / sqrt((double)vv);
        ws[i] = (float)(((double)conv_b[c] - (double)bn1_m[c])*s + (double)bn1_b[c]);
    } else if (i < WS_SH2) {                // bn2 scale
        int c = i - WS_SC2;
        float vv = bn2_v[c] + 1e-5f;
        ws[i] = (float)((double)bn2_g[c] / sqrt((double)vv));
    } else if (i < WS_LIWT) {               // bn2 shift
        int c = i - WS_SH2;
        float vv = bn2_v[c] + 1e-5f;
        double s = (double)bn2_g[c] / sqrt((double)vv);
        ws[i] = (float)((double)bn2_b[c] - (double)bn2_m[c]*s);
    } else if (i < WS_TW1T) {               // li_wT
        int t = i - WS_LIWT; int j = t >> 6, o = t & 63;
        ws[i] = li_w[o*128 + j];
    } else if (i < WS_TW2T) {               // tda_w1T
        int t = i - WS_TW1T; int r = t >> 6, o = t & 63;
        ws[i] = tda_w1[o*150 + r];
    } else if (i < WS_CW1T) {               // tda_w2T
        int t = i - WS_TW2T; int j = t >> 5, o = t & 31;
        ws[i] = tda_w2[o*64 + j];
    } else {                                // cls_w1T
        int t = i - WS_CW1T; int j = t >> 7, c = t & 127;
        ws[i] = cls_w1[c*672 + j];
    }
}

// ---------------- fused kernel: conv + BN + ReLU + projection + LIF scan ------
// one block per b; 5 chunks of 64 t. Per chunk:
//   proj (y_lds -> cur_lds, 16 KB swizzled) ; B ;
//   wave0: scan 64 steps (state in regs, W -> ws) ; all: conv of next chunk ; B
// cur never touches HBM. x double-buffered in registers.
__launch_bounds__(NT, 3)
__global__ void fused_kernel(
    const float* __restrict__ x, const float* __restrict__ conv_w,
    const float* __restrict__ sp_b, const float* __restrict__ ws,
    float* __restrict__ wfeat)
{
    __shared__ float y_lds[128*65];    // 33.3 KB
    __shared__ float cur_lds[64*64];   // 16.4 KB, addr = t*64 + (h ^ ((t&15)<<2))

    const int tid  = threadIdx.x;
    const int b    = blockIdx.x;
    const int ic   = tid & 63;
    const int tg   = tid >> 6;
    const int lane = tid & 63;
    const int h0   = __builtin_amdgcn_readfirstlane((tid >> 6) << 4);

    // ---- per-block constants ----
    float w0[15], w1[15];
    #pragma unroll
    for (int k = 0; k < 15; ++k) {
        w0[k] = conv_w[(2*ic)*15 + k];
        w1[k] = conv_w[(2*ic + 1)*15 + k];
    }
    const float sA = ws[WS_SC1 + 2*ic],     hA = ws[WS_SH1 + 2*ic];
    const float sB = ws[WS_SC1 + 2*ic + 1], hB = ws[WS_SH1 + 2*ic + 1];
    const float4* bp = reinterpret_cast<const float4*>(sp_b + h0);
    const float4 b0v = bp[0], b1v = bp[1], b2v = bp[2], b3v = bp[3];

    const float* __restrict__ spwT = ws;   // [128][64]
    const float* xb = x + (size_t)b * 20480 + ic;
    float* Wb = wfeat + (size_t)b * 1280;

    // ---- scan state (wave 0, lane = h) ----
    float mf = 0.f, ms = 0.f, rlo = 0.f, rhi = 0.f;

    // ---- prologue: chunk 0 x + conv ----
    float xr0[30], xr1[30];
    #pragma unroll
    for (int r = 0; r < 30; ++r) {
        int t = tg*16 - 7 + r;
        xr0[r] = (t >= 0) ? xb[(size_t)t * 64] : 0.f;
    }
    #pragma unroll
    for (int j = 0; j < 16; ++j) {
        float a0 = 0.f, a1 = 0.f;
        #pragma unroll
        for (int k = 0; k < 15; ++k) {
            a0 = fmaf(xr0[j + k], w0[k], a0);
            a1 = fmaf(xr0[j + k], w1[k], a1);
        }
        int tt = tg*16 + j;
        y_lds[(2*ic)*65 + tt]     = fmaxf(fmaf(a0, sA, hA), 0.f);
        y_lds[(2*ic + 1)*65 + tt] = fmaxf(fmaf(a1, sB, hB), 0.f);
    }
    __syncthreads();

    #pragma unroll
    for (int chk = 0; chk < 5; ++chk) {
        float* xn = (chk & 1) ? xr0 : xr1;   // static after full unroll

        // ---- issue next chunk's x loads (fly under the projection) ----
        if (chk < 4) {
            const int tbase = (chk + 1)*64 + tg*16 - 7;   // >= 57: only upper guard
            if (tbase + 29 < 320) {
                #pragma unroll
                for (int r = 0; r < 30; ++r)
                    xn[r] = xb[(size_t)(tbase + r) * 64];
            } else {
                #pragma unroll
                for (int r = 0; r < 30; ++r) {
                    int t = tbase + r;
                    xn[r] = (t < 320) ? xb[(size_t)t * 64] : 0.f;
                }
            }
        }

        // ---- projection: cur[t=lane][h0..h0+15] = spb + sum_c y[t][c]*w[c][h] ----
        {
            float acc[16];
            acc[0]=b0v.x;  acc[1]=b0v.y;  acc[2]=b0v.z;  acc[3]=b0v.w;
            acc[4]=b1v.x;  acc[5]=b1v.y;  acc[6]=b1v.z;  acc[7]=b1v.w;
            acc[8]=b2v.x;  acc[9]=b2v.y;  acc[10]=b2v.z; acc[11]=b2v.w;
            acc[12]=b3v.x; acc[13]=b3v.y; acc[14]=b3v.z; acc[15]=b3v.w;

            #pragma unroll 4
            for (int c = 0; c < 128; ++c) {
                float yv = y_lds[c*65 + lane];
                const float4* wp = reinterpret_cast<const float4*>(spwT + c*64 + h0);
                float4 q0 = wp[0], q1 = wp[1], q2 = wp[2], q3 = wp[3];
                acc[0]  = fmaf(yv, q0.x, acc[0]);
                acc[1]  = fmaf(yv, q0.y, acc[1]);
                acc[2]  = fmaf(yv, q0.z, acc[2]);
                acc[3]  = fmaf(yv, q0.w, acc[3]);
                acc[4]  = fmaf(yv, q1.x, acc[4]);
                acc[5]  = fmaf(yv, q1.y, acc[5]);
                acc[6]  = fmaf(yv, q1.z, acc[6]);
                acc[7]  = fmaf(yv, q1.w, acc[7]);
                acc[8]  = fmaf(yv, q2.x, acc[8]);
                acc[9]  = fmaf(yv, q2.y, acc[9]);
                acc[10] = fmaf(yv, q2.z, acc[10]);
                acc[11] = fmaf(yv, q2.w, acc[11]);
                acc[12] = fmaf(yv, q3.x, acc[12]);
                acc[13] = fmaf(yv, q3.y, acc[13]);
                acc[14] = fmaf(yv, q3.z, acc[14]);
                acc[15] = fmaf(yv, q3.w, acc[15]);
            }
            // swizzled float4 stores into cur_lds (t = lane row)
            const int tsw = (lane & 15) << 2;
            #pragma unroll
            for (int k = 0; k < 4; ++k) {
                float4 v4 = make_float4(acc[4*k], acc[4*k+1], acc[4*k+2], acc[4*k+3]);
                *reinterpret_cast<float4*>(&cur_lds[lane*64 + ((h0 + 4*k) ^ tsw)]) = v4;
            }
        }
        __syncthreads();

        // ---- wave 0: LIF scan of this chunk; all waves: conv of next chunk ----
        if (tid < 64) {
            float sE_lo = 0.f, sE_hi = 0.f;
            #pragma unroll
            for (int gq = 0; gq < 4; ++gq) {
                float v[16];
                #pragma unroll
                for (int q = 0; q < 16; ++q) {
                    int t = gq*16 + q;
                    v[q] = cur_lds[t*64 + (lane ^ ((t & 15) << 2))];
                }
                float slo = 0.f, shi = 0.f;
                #pragma unroll
                for (int q = 0; q < 16; ++q) {
                    float c = v[q];
                    mf = fmaf(0.5f, mf, c);
                    bool sf = mf >= 0.5f;
                    ms = fmaf(0.9f, ms, c);
                    bool ss = ms >= 1.0f;
                    mf = sf ? 0.f : mf;
                    ms = ss ? 0.f : ms;
                    rlo = fmaf(0.9f, rlo, sf ? 1.f : 0.f);
                    rhi = fmaf(0.9f, rhi, ss ? 1.f : 0.f);
                    slo += rlo; shi += rhi;
                }
                if ((gq & 1) == 0) {
                    sE_lo = slo; sE_hi = shi;
                } else {
                    int wdx = chk*2 + (gq >> 1);
                    Wb[wdx*128 + lane]      = slo - sE_lo;
                    Wb[wdx*128 + 64 + lane] = shi - sE_hi;
                }
            }
        }
        if (chk < 4) {
            #pragma unroll
            for (int j = 0; j < 16; ++j) {
                float a0 = 0.f, a1 = 0.f;
                #pragma unroll
                for (int k = 0; k < 15; ++k) {
                    a0 = fmaf(xn[j + k], w0[k], a0);
                    a1 = fmaf(xn[j + k], w1[k], a1);
                }
                int tt = tg*16 + j;
                y_lds[(2*ic)*65 + tt]     = fmaxf(fmaf(a0, sA, hA), 0.f);
                y_lds[(2*ic + 1)*65 + tt] = fmaxf(fmaf(a1, sB, hB), 0.f);
            }
        }
        __syncthreads();
    }
}

// ---------------- kernel C: classifier epilogue, one block per b ----------------
__global__ void epilogue_kernel(
    const float* __restrict__ tda,    const float* __restrict__ li_b,
    const float* __restrict__ tda_b1, const float* __restrict__ tda_b2,
    const float* __restrict__ cls_b1, const float* __restrict__ cls_w2,
    const float* __restrict__ cls_b2, const float* __restrict__ ws,
    const float* __restrict__ W,      float* __restrict__ out)
{
    __shared__ float Wl[1280];
    __shared__ float t1[64], tf[32], dp[640], h1[128];
    const int b = blockIdx.x, tid = threadIdx.x;

    for (int i = tid; i < 1280; i += NT)
        Wl[i] = W[(size_t)b*1280 + i];
    __syncthreads();

    const float* __restrict__ liwT = ws + WS_LIWT;
    const float* __restrict__ tw1T = ws + WS_TW1T;
    const float* __restrict__ tw2T = ws + WS_TW2T;
    const float* __restrict__ cw1T = ws + WS_CW1T;
    const float* tdab = tda + b*150;

    if (tid < 64) {                     // tda layer 1
        float acc = tda_b1[tid];
        for (int i2 = 0; i2 < 150; ++i2)
            acc = fmaf(tdab[i2], tw1T[i2*64 + tid], acc);
        t1[tid] = fmaxf(acc, 0.f);
    }
    __syncthreads();
    if (tid < 32) {                     // tda layer 2
        float acc = tda_b2[tid];
        #pragma unroll 8
        for (int j = 0; j < 64; ++j)
            acc = fmaf(t1[j], tw2T[j*32 + tid], acc);
        tf[tid] = fmaxf(acc, 0.f);
    }
    // dp_feat = (1/16) * (li_w @ W + li_b * Wg)
    {
        int o = tid & 63;
        for (int w = tid >> 6; w < 10; w += 4) {
            float acc = li_b[o] * ws[WS_WG + w];
            #pragma unroll 4
            for (int j = 0; j < 128; ++j)
                acc = fmaf(Wl[w*128 + j], liwT[j*64 + o], acc);
            dp[w*64 + o] = 0.0625f * acc;
        }
    }
    __syncthreads();
    if (tid < 128) {                    // classifier layer 1 + BN2 + ReLU
        float acc = cls_b1[tid];
        for (int j = 0; j < 640; ++j)
            acc = fmaf(dp[j], cw1T[j*128 + tid], acc);
        #pragma unroll 4
        for (int j = 0; j < 32; ++j)
            acc = fmaf(tf[j], cw1T[(640 + j)*128 + tid], acc);
        float s2 = ws[WS_SC2 + tid], sh2 = ws[WS_SH2 + tid];
        h1[tid] = fmaxf(fmaf(acc, s2, sh2), 0.f);
    }
    __syncthreads();
    if (tid < 4) {                      // classifier layer 2
        float acc = cls_b2[tid];
        for (int c = 0; c < 128; ++c)
            acc = fmaf(h1[c], cls_w2[tid*128 + c], acc);
        out[b*4 + tid] = acc;
    }
}

extern "C" void kernel_launch(void* const* d_in, const int* in_sizes, int n_in,
                              void* d_out, int out_size, void* d_ws, size_t ws_size,
                              hipStream_t stream) {
    const float* x      = (const float*)d_in[0];
    const float* tda    = (const float*)d_in[1];
    const float* conv_w = (const float*)d_in[2];
    const float* conv_b = (const float*)d_in[3];
    const float* bn1_g  = (const float*)d_in[4];
    const float* bn1_b  = (const float*)d_in[5];
    const float* bn1_m  = (const float*)d_in[6];
    const float* bn1_v  = (const float*)d_in[7];
    const float* sp_w   = (const float*)d_in[8];
    const float* sp_b   = (const float*)d_in[9];
    const float* li_w   = (const float*)d_in[10];
    const float* li_b   = (const float*)d_in[11];
    const float* tda_w1 = (const float*)d_in[12];
    const float* tda_b1 = (const float*)d_in[13];
    const float* tda_w2 = (const float*)d_in[14];
    const float* tda_b2 = (const float*)d_in[15];
    const float* cls_w1 = (const float*)d_in[16];
    const float* cls_b1 = (const float*)d_in[17];
    const float* bn2_g  = (const float*)d_in[18];
    const float* bn2_b  = (const float*)d_in[19];
    const float* bn2_m  = (const float*)d_in[20];
    const float* bn2_v  = (const float*)d_in[21];
    const float* cls_w2 = (const float*)d_in[22];
    const float* cls_b2 = (const float*)d_in[23];
    float* ws  = (float*)d_ws;
    float* out = (float*)d_out;

    const int B = in_sizes[0] / (320 * 64);   // 2048

    prep_kernel<<<(WS_TOTAL + 1 + NT - 1)/NT, NT, 0, stream>>>(
        conv_b, bn1_g, bn1_b, bn1_m, bn1_v, sp_w,
        li_w, tda_w1, tda_w2, cls_w1,
        bn2_g, bn2_b, bn2_m, bn2_v, ws);

    fused_kernel<<<B, NT, 0, stream>>>(
        x, conv_w, sp_b, ws, ws + WS_WBASE);

    epilogue_kernel<<<B, NT, 0, stream>>>(
        tda, li_b, tda_b1, tda_b2, cls_b1, cls_w2, cls_b2,
        ws, ws + WS_WBASE, out);
}